// Round 1
// baseline (661.995 us; speedup 1.0000x reference)
//
#include <hip/hip_runtime.h>
#include <math.h>

#define NN 50000
#define NE 800000
#define FD 256
#define HD 256
#define OD 64
#define NCH ((NN + 255) / 256)   // 196 chunks for prefix sum

// ---------------- CSR build ----------------

__global__ void k_count(const int* __restrict__ dst, int* __restrict__ deg) {
    int e = blockIdx.x * 256 + threadIdx.x;
    if (e < NE) atomicAdd(&deg[dst[e]], 1);
}

__global__ void k_chunk_sum(const int* __restrict__ deg, int* __restrict__ chunkSum) {
    __shared__ int s[256];
    int g = blockIdx.x * 256 + threadIdx.x;
    s[threadIdx.x] = (g < NN) ? deg[g] : 0;
    __syncthreads();
    for (int o = 128; o > 0; o >>= 1) {
        if (threadIdx.x < o) s[threadIdx.x] += s[threadIdx.x + o];
        __syncthreads();
    }
    if (threadIdx.x == 0) chunkSum[blockIdx.x] = s[0];
}

__global__ void k_scan_chunks(const int* __restrict__ chunkSum, int* __restrict__ chunkOff) {
    if (threadIdx.x == 0 && blockIdx.x == 0) {
        int acc = 0;
        for (int i = 0; i < NCH; ++i) { chunkOff[i] = acc; acc += chunkSum[i]; }
    }
}

__global__ void k_scan_write(const int* __restrict__ deg, const int* __restrict__ chunkOff,
                             int* __restrict__ offsets, int* __restrict__ cursor) {
    __shared__ int s[256];
    int b = blockIdx.x, t = threadIdx.x;
    int g = b * 256 + t;
    int v = (g < NN) ? deg[g] : 0;
    s[t] = v;
    __syncthreads();
    for (int o = 1; o < 256; o <<= 1) {
        int x = (t >= o) ? s[t - o] : 0;
        __syncthreads();
        s[t] += x;
        __syncthreads();
    }
    int excl = s[t] - v + chunkOff[b];
    if (g <= NN) {
        offsets[g] = excl;
        if (g < NN) cursor[g] = excl;
    }
}

__global__ void k_scatter(const int* __restrict__ src, const int* __restrict__ dst,
                          const float* __restrict__ w, int* __restrict__ cursor,
                          int* __restrict__ psrc, float* __restrict__ pw) {
    int e = blockIdx.x * 256 + threadIdx.x;
    if (e < NE) {
        int d = dst[e];
        int p = atomicAdd(&cursor[d], 1);
        psrc[p] = src[e];
        pw[p]  = w[e];
    }
}

// ---------------- GEMM1: support = input @ hidden_weight  [NN,256] ----------------

__global__ __launch_bounds__(256) void k_gemm1(const float* __restrict__ A,
                                               const float* __restrict__ B,
                                               float* __restrict__ C) {
    __shared__ float As[64][33];
    __shared__ float Bs[32][65];
    int row0 = blockIdx.x * 64;
    int col0 = blockIdx.y * 64;
    int tid = threadIdx.x;
    int tx = tid % 16, ty = tid / 16;
    float acc[4][4] = {};
    for (int k0 = 0; k0 < FD; k0 += 32) {
        #pragma unroll
        for (int i = 0; i < 2; ++i) {
            int idx = tid + i * 256;      // 0..511
            int r = idx >> 3;             // 64 rows
            int kk = (idx & 7) * 4;
            int gr = row0 + r;
            float4 v = make_float4(0.f, 0.f, 0.f, 0.f);
            if (gr < NN) v = *reinterpret_cast<const float4*>(&A[(size_t)gr * FD + k0 + kk]);
            As[r][kk + 0] = v.x; As[r][kk + 1] = v.y; As[r][kk + 2] = v.z; As[r][kk + 3] = v.w;
        }
        #pragma unroll
        for (int i = 0; i < 2; ++i) {
            int idx = tid + i * 256;
            int r = idx >> 4;             // 32 k-rows
            int cc = (idx & 15) * 4;
            float4 v = *reinterpret_cast<const float4*>(&B[(size_t)(k0 + r) * HD + col0 + cc]);
            Bs[r][cc + 0] = v.x; Bs[r][cc + 1] = v.y; Bs[r][cc + 2] = v.z; Bs[r][cc + 3] = v.w;
        }
        __syncthreads();
        #pragma unroll
        for (int kk = 0; kk < 32; ++kk) {
            float a[4], b[4];
            #pragma unroll
            for (int i = 0; i < 4; ++i) a[i] = As[ty * 4 + i][kk];
            #pragma unroll
            for (int j = 0; j < 4; ++j) b[j] = Bs[kk][tx * 4 + j];
            #pragma unroll
            for (int i = 0; i < 4; ++i)
                #pragma unroll
                for (int j = 0; j < 4; ++j)
                    acc[i][j] = fmaf(a[i], b[j], acc[i][j]);
        }
        __syncthreads();
    }
    #pragma unroll
    for (int i = 0; i < 4; ++i) {
        int gr = row0 + ty * 4 + i;
        if (gr < NN) {
            float4 v = make_float4(acc[i][0], acc[i][1], acc[i][2], acc[i][3]);
            *reinterpret_cast<float4*>(&C[(size_t)gr * HD + col0 + tx * 4]) = v;
        }
    }
}

// ---------------- SpMM1 + bias + relu: hidden_g = relu(A @ support + b) ----------------

__global__ __launch_bounds__(64) void k_spmm1(const int* __restrict__ off, const int* __restrict__ psrc,
                                              const float* __restrict__ pw,
                                              const float* __restrict__ support,
                                              const float* __restrict__ bias,
                                              float* __restrict__ hidden_g) {
    int d = blockIdx.x;
    int lane = threadIdx.x;
    int e0 = off[d], e1 = off[d + 1];
    const float4* S = reinterpret_cast<const float4*>(support);
    float4 acc = make_float4(0.f, 0.f, 0.f, 0.f);
    for (int e = e0; e < e1; ++e) {
        int s = psrc[e];
        float w = pw[e];
        float4 v = S[(size_t)s * 64 + lane];
        acc.x = fmaf(w, v.x, acc.x);
        acc.y = fmaf(w, v.y, acc.y);
        acc.z = fmaf(w, v.z, acc.z);
        acc.w = fmaf(w, v.w, acc.w);
    }
    float4 b = reinterpret_cast<const float4*>(bias)[lane];
    float4 r;
    r.x = fmaxf(acc.x + b.x, 0.f);
    r.y = fmaxf(acc.y + b.y, 0.f);
    r.z = fmaxf(acc.z + b.z, 0.f);
    r.w = fmaxf(acc.w + b.w, 0.f);
    reinterpret_cast<float4*>(hidden_g)[(size_t)d * 64 + lane] = r;
}

// ---------------- GEMM2: [NN,256] @ [256,128] (cols = [mean_w | log_std_w]) ----------------
// MLP=false: A=hidden_g, out = gcn_pre [NN,128]
// MLP=true:  A=relu(support+hbias), out = d_out (z_mean area cols<64, z_log_std area cols>=64) + biases

template <bool MLP>
__global__ __launch_bounds__(256) void k_gemm2(const float* __restrict__ A,
                                               const float* __restrict__ Wm,
                                               const float* __restrict__ Wl,
                                               const float* __restrict__ hbias,
                                               const float* __restrict__ mbias,
                                               const float* __restrict__ lbias,
                                               float* __restrict__ out) {
    __shared__ float As[64][33];
    __shared__ float Bs[32][129];
    int row0 = blockIdx.x * 64;
    int tid = threadIdx.x;
    int tx = tid % 16;   // col group: tx*8 .. +7  (128 cols)
    int ty = tid / 16;   // row group: ty*4 .. +3  (64 rows)
    float acc[4][8] = {};
    for (int k0 = 0; k0 < HD; k0 += 32) {
        #pragma unroll
        for (int i = 0; i < 2; ++i) {
            int idx = tid + i * 256;
            int r = idx >> 3;
            int kk = (idx & 7) * 4;
            int gr = row0 + r;
            float4 v = make_float4(0.f, 0.f, 0.f, 0.f);
            if (gr < NN) v = *reinterpret_cast<const float4*>(&A[(size_t)gr * HD + k0 + kk]);
            if (MLP) {
                float4 b = *reinterpret_cast<const float4*>(&hbias[k0 + kk]);
                v.x = fmaxf(v.x + b.x, 0.f);
                v.y = fmaxf(v.y + b.y, 0.f);
                v.z = fmaxf(v.z + b.z, 0.f);
                v.w = fmaxf(v.w + b.w, 0.f);
            }
            As[r][kk + 0] = v.x; As[r][kk + 1] = v.y; As[r][kk + 2] = v.z; As[r][kk + 3] = v.w;
        }
        #pragma unroll
        for (int i = 0; i < 4; ++i) {
            int idx = tid + i * 256;          // 0..1023
            int r = idx >> 5;                 // 32 k-rows
            int cc = (idx & 31) * 4;          // 0..124
            const float* Wsrc = (cc < 64) ? Wm : Wl;
            int c2 = (cc < 64) ? cc : cc - 64;
            float4 v = *reinterpret_cast<const float4*>(&Wsrc[(size_t)(k0 + r) * OD + c2]);
            Bs[r][cc + 0] = v.x; Bs[r][cc + 1] = v.y; Bs[r][cc + 2] = v.z; Bs[r][cc + 3] = v.w;
        }
        __syncthreads();
        #pragma unroll
        for (int kk = 0; kk < 32; ++kk) {
            float a[4], b[8];
            #pragma unroll
            for (int i = 0; i < 4; ++i) a[i] = As[ty * 4 + i][kk];
            #pragma unroll
            for (int j = 0; j < 8; ++j) b[j] = Bs[kk][tx * 8 + j];
            #pragma unroll
            for (int i = 0; i < 4; ++i)
                #pragma unroll
                for (int j = 0; j < 8; ++j)
                    acc[i][j] = fmaf(a[i], b[j], acc[i][j]);
        }
        __syncthreads();
    }
    #pragma unroll
    for (int i = 0; i < 4; ++i) {
        int gr = row0 + ty * 4 + i;
        if (gr >= NN) continue;
        if (MLP) {
            // tx<8 -> all 8 cols in mean region; tx>=8 -> all in log_std region
            if (tx < 8) {
                int c = tx * 8;
                float4 v0 = make_float4(acc[i][0] + mbias[c + 0], acc[i][1] + mbias[c + 1],
                                        acc[i][2] + mbias[c + 2], acc[i][3] + mbias[c + 3]);
                float4 v1 = make_float4(acc[i][4] + mbias[c + 4], acc[i][5] + mbias[c + 5],
                                        acc[i][6] + mbias[c + 6], acc[i][7] + mbias[c + 7]);
                *reinterpret_cast<float4*>(&out[(size_t)gr * OD + c])     = v0;
                *reinterpret_cast<float4*>(&out[(size_t)gr * OD + c + 4]) = v1;
            } else {
                int c = tx * 8 - 64;
                float* ol = out + (size_t)NN * OD;
                float4 v0 = make_float4(acc[i][0] + lbias[c + 0], acc[i][1] + lbias[c + 1],
                                        acc[i][2] + lbias[c + 2], acc[i][3] + lbias[c + 3]);
                float4 v1 = make_float4(acc[i][4] + lbias[c + 4], acc[i][5] + lbias[c + 5],
                                        acc[i][6] + lbias[c + 6], acc[i][7] + lbias[c + 7]);
                *reinterpret_cast<float4*>(&ol[(size_t)gr * OD + c])     = v0;
                *reinterpret_cast<float4*>(&ol[(size_t)gr * OD + c + 4]) = v1;
            }
        } else {
            float4 v0 = make_float4(acc[i][0], acc[i][1], acc[i][2], acc[i][3]);
            float4 v1 = make_float4(acc[i][4], acc[i][5], acc[i][6], acc[i][7]);
            *reinterpret_cast<float4*>(&out[(size_t)gr * 128 + tx * 8])     = v0;
            *reinterpret_cast<float4*>(&out[(size_t)gr * 128 + tx * 8 + 4]) = v1;
        }
    }
}

// ---------------- SpMM2 (128-dim) + mixture combine (in place over d_out) ----------------

__global__ __launch_bounds__(64) void k_spmm2(const int* __restrict__ off, const int* __restrict__ psrc,
                                              const float* __restrict__ pw,
                                              const float* __restrict__ gcn_pre,
                                              const float* __restrict__ mixw,
                                              float* __restrict__ out) {
    int d = blockIdx.x;
    int lane = threadIdx.x;
    int e0 = off[d], e1 = off[d + 1];
    const float2* G = reinterpret_cast<const float2*>(gcn_pre);
    float2 acc = make_float2(0.f, 0.f);
    for (int e = e0; e < e1; ++e) {
        int s = psrc[e];
        float w = pw[e];
        float2 v = G[(size_t)s * 64 + lane];
        acc.x = fmaf(w, v.x, acc.x);
        acc.y = fmaf(w, v.y, acc.y);
    }
    float mw = mixw[0];
    float mr = 1.f / (1.f + expf(-mw));
    int c = lane * 2;
    if (c < 64) {
        float* om = out + (size_t)d * OD + c;
        om[0] = acc.x * mw + om[0] * (1.f - mw);
        om[1] = acc.y * mw + om[1] * (1.f - mw);
    } else {
        float* ol = out + (size_t)NN * OD + (size_t)d * OD + (c - 64);
        ol[0] = acc.x * mr + ol[0] * (1.f - mr);
        ol[1] = acc.y * mr + ol[1] * (1.f - mr);
    }
}

// ---------------- host ----------------

extern "C" void kernel_launch(void* const* d_in, const int* in_sizes, int n_in,
                              void* d_out, int out_size, void* d_ws, size_t ws_size,
                              hipStream_t stream) {
    const float* input = (const float*)d_in[0];
    const int*   ei    = (const int*)d_in[1];     // [2, NE]
    const float* ew    = (const float*)d_in[2];
    const float* mixw  = (const float*)d_in[3];
    const float* hw    = (const float*)d_in[4];   // [256,256]
    const float* hb    = (const float*)d_in[5];
    const float* mw_   = (const float*)d_in[6];   // [256,64]
    const float* mb    = (const float*)d_in[7];
    const float* lw    = (const float*)d_in[8];   // [256,64]
    const float* lb    = (const float*)d_in[9];
    float* out = (float*)d_out;

    const int* src = ei;
    const int* dst = ei + NE;

    char* ws = (char*)d_ws;
    size_t off = 0;
    auto alloc = [&](size_t bytes) -> void* {
        void* p = ws + off;
        off += (bytes + 255) & ~(size_t)255;
        return p;
    };
    int*   deg      = (int*)alloc((size_t)NN * 4);
    int*   offsets  = (int*)alloc((size_t)(NN + 1) * 4);
    int*   cursor   = (int*)alloc((size_t)NN * 4);
    int*   chunkSum = (int*)alloc((size_t)NCH * 4);
    int*   chunkOff = (int*)alloc((size_t)NCH * 4);
    int*   psrc     = (int*)alloc((size_t)NE * 4);
    float* pw       = (float*)alloc((size_t)NE * 4);
    float* support  = (float*)alloc((size_t)NN * HD * 4);
    float* hidden_g = (float*)alloc((size_t)NN * HD * 4);
    float* gcn_pre  = (float*)alloc((size_t)NN * 128 * 4);

    hipMemsetAsync(deg, 0, (size_t)NN * 4, stream);

    int eblk = (NE + 255) / 256;
    k_count<<<eblk, 256, 0, stream>>>(dst, deg);
    k_chunk_sum<<<NCH, 256, 0, stream>>>(deg, chunkSum);
    k_scan_chunks<<<1, 64, 0, stream>>>(chunkSum, chunkOff);
    k_scan_write<<<NCH, 256, 0, stream>>>(deg, chunkOff, offsets, cursor);
    k_scatter<<<eblk, 256, 0, stream>>>(src, dst, ew, cursor, psrc, pw);

    // GEMM1: support = input @ hw
    k_gemm1<<<dim3((NN + 63) / 64, HD / 64), 256, 0, stream>>>(input, hw, support);

    // SpMM1 + bias + relu
    k_spmm1<<<NN, 64, 0, stream>>>(offsets, psrc, pw, support, hb, hidden_g);

    // GEMM2 (GCN): gcn_pre = hidden_g @ [mw|lw]
    k_gemm2<false><<<(NN + 63) / 64, 256, 0, stream>>>(hidden_g, mw_, lw, hb, mb, lb, gcn_pre);

    // GEMM2 (MLP): d_out = relu(support+hb) @ [mw|lw] + [mb|lb]
    k_gemm2<true><<<(NN + 63) / 64, 256, 0, stream>>>(support, mw_, lw, hb, mb, lb, out);

    // SpMM2 + mixture combine (in place)
    k_spmm2<<<NN, 64, 0, stream>>>(offsets, psrc, pw, gcn_pre, mixw, out);
}

// Round 2
// 259.619 us; speedup vs baseline: 2.5499x; 2.5499x over previous
//
#include <hip/hip_runtime.h>
#include <math.h>

#define NN 50000
#define NE 800000
#define KD 256
#define OD 64
#define NCH ((NN + 255) / 256)

using bf16x8 = __attribute__((ext_vector_type(8))) short;
using f32x4  = __attribute__((ext_vector_type(4))) float;

__device__ __forceinline__ unsigned short f2b(float x) {
    union { float f; unsigned u; } c; c.f = x;
    unsigned r = (c.u + 0x7FFF + ((c.u >> 16) & 1)) >> 16;
    return (unsigned short)r;
}
__device__ __forceinline__ float b2f(unsigned short b) {
    union { unsigned u; float f; } c; c.u = ((unsigned)b) << 16;
    return c.f;
}

// ---------------- CSR build ----------------

__global__ void k_count(const int* __restrict__ dst, int* __restrict__ deg) {
    int e = blockIdx.x * 256 + threadIdx.x;
    if (e < NE) atomicAdd(&deg[dst[e]], 1);
}

__global__ void k_chunk_sum(const int* __restrict__ deg, int* __restrict__ chunkSum) {
    __shared__ int s[256];
    int g = blockIdx.x * 256 + threadIdx.x;
    s[threadIdx.x] = (g < NN) ? deg[g] : 0;
    __syncthreads();
    for (int o = 128; o > 0; o >>= 1) {
        if (threadIdx.x < o) s[threadIdx.x] += s[threadIdx.x + o];
        __syncthreads();
    }
    if (threadIdx.x == 0) chunkSum[blockIdx.x] = s[0];
}

__global__ void k_scan_chunks(const int* __restrict__ chunkSum, int* __restrict__ chunkOff) {
    if (threadIdx.x == 0 && blockIdx.x == 0) {
        int acc = 0;
        for (int i = 0; i < NCH; ++i) { chunkOff[i] = acc; acc += chunkSum[i]; }
    }
}

__global__ void k_scan_write(const int* __restrict__ deg, const int* __restrict__ chunkOff,
                             int* __restrict__ offsets, int* __restrict__ cursor) {
    __shared__ int s[256];
    int b = blockIdx.x, t = threadIdx.x;
    int g = b * 256 + t;
    int v = (g < NN) ? deg[g] : 0;
    s[t] = v;
    __syncthreads();
    for (int o = 1; o < 256; o <<= 1) {
        int x = (t >= o) ? s[t - o] : 0;
        __syncthreads();
        s[t] += x;
        __syncthreads();
    }
    int excl = s[t] - v + chunkOff[b];
    if (g <= NN) {
        offsets[g] = excl;
        if (g < NN) cursor[g] = excl;
    }
}

__global__ void k_scatter(const int* __restrict__ src, const int* __restrict__ dst,
                          const float* __restrict__ w, int* __restrict__ cursor,
                          int* __restrict__ psrc, float* __restrict__ pw) {
    int e = blockIdx.x * 256 + threadIdx.x;
    if (e < NE) {
        int d = dst[e];
        int p = atomicAdd(&cursor[d], 1);
        psrc[p] = src[e];
        pw[p]  = w[e];
    }
}

// ---------------- weight transpose + bf16 convert (one-time, tiny) ----------------
// Wht  [256][256]: Wht[n][k] = bf16(hw[k][n])
// Wmlt [128][256]: n<64 -> mean_w[k][n], n>=64 -> log_std_w[k][n-64]

__global__ void k_convW(const float* __restrict__ hw, const float* __restrict__ mw_,
                        const float* __restrict__ lw,
                        unsigned short* __restrict__ Wht, unsigned short* __restrict__ Wmlt) {
    int idx = blockIdx.x * 256 + threadIdx.x;
    if (idx < 256 * 256) {
        int n = idx >> 8, k = idx & 255;
        Wht[(size_t)n * 256 + k] = f2b(hw[(size_t)k * 256 + n]);
    }
    if (idx < 128 * 256) {
        int n = idx >> 8, k = idx & 255;
        float v = (n < 64) ? mw_[(size_t)k * 64 + n] : lw[(size_t)k * 64 + (n - 64)];
        Wmlt[(size_t)n * 256 + k] = f2b(v);
    }
}

// ---------------- MFMA GEMM: [NN,256] @ Bt^T, 64x64 tile, 4 waves ----------------
// AM: 0 = A is f32 (convert on the fly); 1 = A is bf16; 2 = A is bf16, apply +hbias,relu
// EM: 0 = store bf16 to Out with row stride ldOut; 1 = store f32+bias into d_out regions

template <int AM, int EM>
__global__ __launch_bounds__(256) void k_gemm(const void* __restrict__ Ap,
                                              const unsigned short* __restrict__ Bt,
                                              const float* __restrict__ hbias,
                                              const float* __restrict__ mbias,
                                              const float* __restrict__ lbias,
                                              void* __restrict__ Outp,
                                              int ldOut) {
    __shared__ unsigned short As[64 * 64];
    __shared__ unsigned short Bs[64 * 64];
    const int tid = threadIdx.x;
    const int row0 = blockIdx.x * 64;
    const int n0 = blockIdx.y * 64;
    const int lane = tid & 63;
    const int w = tid >> 6, wm = w >> 1, wn = w & 1;
    const int lr = lane & 15, lg = lane >> 4;

    const int r = tid >> 2;      // staging row 0..63
    const int q = tid & 3;       // k-quarter (16 bf16)

    f32x4 acc[2][2] = {};

    for (int k0 = 0; k0 < KD; k0 += 64) {
        // ---- stage A tile (64 rows x 64 k, bf16, XOR-swizzled 16B slots) ----
        {
            int gr = row0 + r;
            unsigned short tmp[16];
            if (AM == 0) {
                const float* A = (const float*)Ap;
                if (gr < NN) {
                    #pragma unroll
                    for (int i = 0; i < 4; ++i) {
                        float4 v = *reinterpret_cast<const float4*>(
                            &A[(size_t)gr * KD + k0 + q * 16 + i * 4]);
                        tmp[i * 4 + 0] = f2b(v.x); tmp[i * 4 + 1] = f2b(v.y);
                        tmp[i * 4 + 2] = f2b(v.z); tmp[i * 4 + 3] = f2b(v.w);
                    }
                } else {
                    #pragma unroll
                    for (int i = 0; i < 16; ++i) tmp[i] = 0;
                }
            } else {
                const unsigned short* A = (const unsigned short*)Ap;
                if (gr < NN) {
                    uint4 u0 = *reinterpret_cast<const uint4*>(&A[(size_t)gr * KD + k0 + q * 16]);
                    uint4 u1 = *reinterpret_cast<const uint4*>(&A[(size_t)gr * KD + k0 + q * 16 + 8]);
                    *reinterpret_cast<uint4*>(&tmp[0]) = u0;
                    *reinterpret_cast<uint4*>(&tmp[8]) = u1;
                    if (AM == 2) {
                        #pragma unroll
                        for (int i = 0; i < 16; ++i) {
                            float f = b2f(tmp[i]) + hbias[k0 + q * 16 + i];
                            tmp[i] = f2b(fmaxf(f, 0.f));
                        }
                    }
                } else {
                    #pragma unroll
                    for (int i = 0; i < 16; ++i) tmp[i] = 0;
                }
            }
            int s0 = (q * 2) ^ (r & 7);
            int s1 = (q * 2 + 1) ^ (r & 7);
            *reinterpret_cast<uint4*>(&As[r * 64 + s0 * 8]) = *reinterpret_cast<uint4*>(&tmp[0]);
            *reinterpret_cast<uint4*>(&As[r * 64 + s1 * 8]) = *reinterpret_cast<uint4*>(&tmp[8]);
        }
        // ---- stage B tile (Bt is [N][K] bf16 row-major -> coalesced) ----
        {
            const unsigned short* B = Bt + (size_t)(n0 + r) * KD + k0 + q * 16;
            uint4 u0 = *reinterpret_cast<const uint4*>(B);
            uint4 u1 = *reinterpret_cast<const uint4*>(B + 8);
            int s0 = (q * 2) ^ (r & 7);
            int s1 = (q * 2 + 1) ^ (r & 7);
            *reinterpret_cast<uint4*>(&Bs[r * 64 + s0 * 8]) = u0;
            *reinterpret_cast<uint4*>(&Bs[r * 64 + s1 * 8]) = u1;
        }
        __syncthreads();
        // ---- MFMA: each wave does 32x32 output, 2 K-slices of 32 ----
        #pragma unroll
        for (int ks = 0; ks < 2; ++ks) {
            int c16 = ks * 4 + lg;
            int ra0 = wm * 32 + lr;
            int ra1 = wm * 32 + 16 + lr;
            int rb0 = wn * 32 + lr;
            int rb1 = wn * 32 + 16 + lr;
            bf16x8 a0 = *reinterpret_cast<const bf16x8*>(&As[ra0 * 64 + (c16 ^ (ra0 & 7)) * 8]);
            bf16x8 a1 = *reinterpret_cast<const bf16x8*>(&As[ra1 * 64 + (c16 ^ (ra1 & 7)) * 8]);
            bf16x8 b0 = *reinterpret_cast<const bf16x8*>(&Bs[rb0 * 64 + (c16 ^ (rb0 & 7)) * 8]);
            bf16x8 b1 = *reinterpret_cast<const bf16x8*>(&Bs[rb1 * 64 + (c16 ^ (rb1 & 7)) * 8]);
            acc[0][0] = __builtin_amdgcn_mfma_f32_16x16x32_bf16(a0, b0, acc[0][0], 0, 0, 0);
            acc[0][1] = __builtin_amdgcn_mfma_f32_16x16x32_bf16(a0, b1, acc[0][1], 0, 0, 0);
            acc[1][0] = __builtin_amdgcn_mfma_f32_16x16x32_bf16(a1, b0, acc[1][0], 0, 0, 0);
            acc[1][1] = __builtin_amdgcn_mfma_f32_16x16x32_bf16(a1, b1, acc[1][1], 0, 0, 0);
        }
        __syncthreads();
    }
    // ---- epilogue: C/D layout col=lane&15, row=(lane>>4)*4+reg ----
    #pragma unroll
    for (int fm = 0; fm < 2; ++fm) {
        #pragma unroll
        for (int j = 0; j < 4; ++j) {
            int grow = row0 + wm * 32 + fm * 16 + lg * 4 + j;
            if (grow >= NN) continue;
            #pragma unroll
            for (int fn = 0; fn < 2; ++fn) {
                int gcol = n0 + wn * 32 + fn * 16 + lr;
                float v = acc[fm][fn][j];
                if (EM == 0) {
                    ((unsigned short*)Outp)[(size_t)grow * ldOut + gcol] = f2b(v);
                } else {
                    float* out = (float*)Outp;
                    int region = gcol >> 6;
                    int oc = gcol & 63;
                    float b = region ? lbias[oc] : mbias[oc];
                    out[(size_t)region * NN * OD + (size_t)grow * OD + oc] = v + b;
                }
            }
        }
    }
}

// ---------------- SpMM1 + bias + relu (bf16 gather, bf16 out), unroll 4 ----------------

__global__ __launch_bounds__(64) void k_spmm1(const int* __restrict__ off, const int* __restrict__ psrc,
                                              const float* __restrict__ pw,
                                              const unsigned short* __restrict__ sup,
                                              const float* __restrict__ bias,
                                              unsigned short* __restrict__ hg) {
    int d = blockIdx.x;
    int lane = threadIdx.x;
    int e0 = off[d], e1 = off[d + 1];
    float a0 = 0.f, a1 = 0.f, a2 = 0.f, a3 = 0.f;
    const ushort4* S = reinterpret_cast<const ushort4*>(sup);   // 64 ushort4 per row
    int e = e0;
    for (; e + 4 <= e1; e += 4) {
        int s0 = psrc[e], s1 = psrc[e + 1], s2 = psrc[e + 2], s3 = psrc[e + 3];
        float w0 = pw[e], w1 = pw[e + 1], w2 = pw[e + 2], w3 = pw[e + 3];
        ushort4 v0 = S[(size_t)s0 * 64 + lane];
        ushort4 v1 = S[(size_t)s1 * 64 + lane];
        ushort4 v2 = S[(size_t)s2 * 64 + lane];
        ushort4 v3 = S[(size_t)s3 * 64 + lane];
        a0 += w0 * b2f(v0.x) + w1 * b2f(v1.x) + w2 * b2f(v2.x) + w3 * b2f(v3.x);
        a1 += w0 * b2f(v0.y) + w1 * b2f(v1.y) + w2 * b2f(v2.y) + w3 * b2f(v3.y);
        a2 += w0 * b2f(v0.z) + w1 * b2f(v1.z) + w2 * b2f(v2.z) + w3 * b2f(v3.z);
        a3 += w0 * b2f(v0.w) + w1 * b2f(v1.w) + w2 * b2f(v2.w) + w3 * b2f(v3.w);
    }
    for (; e < e1; ++e) {
        int s = psrc[e];
        float w = pw[e];
        ushort4 v = S[(size_t)s * 64 + lane];
        a0 += w * b2f(v.x); a1 += w * b2f(v.y); a2 += w * b2f(v.z); a3 += w * b2f(v.w);
    }
    float4 b = *reinterpret_cast<const float4*>(&bias[lane * 4]);
    ushort4 o;
    o.x = f2b(fmaxf(a0 + b.x, 0.f));
    o.y = f2b(fmaxf(a1 + b.y, 0.f));
    o.z = f2b(fmaxf(a2 + b.z, 0.f));
    o.w = f2b(fmaxf(a3 + b.w, 0.f));
    reinterpret_cast<ushort4*>(hg)[(size_t)d * 64 + lane] = o;
}

// ---------------- SpMM2 (bf16 gather, 128 dims) + mixture combine in place ----------------

__global__ __launch_bounds__(64) void k_spmm2(const int* __restrict__ off, const int* __restrict__ psrc,
                                              const float* __restrict__ pw,
                                              const unsigned short* __restrict__ gp,
                                              const float* __restrict__ mixw,
                                              float* __restrict__ out) {
    int d = blockIdx.x;
    int lane = threadIdx.x;
    int e0 = off[d], e1 = off[d + 1];
    float a0 = 0.f, a1 = 0.f;
    const ushort2* G = reinterpret_cast<const ushort2*>(gp);    // 64 ushort2 per row
    int e = e0;
    for (; e + 4 <= e1; e += 4) {
        int s0 = psrc[e], s1 = psrc[e + 1], s2 = psrc[e + 2], s3 = psrc[e + 3];
        float w0 = pw[e], w1 = pw[e + 1], w2 = pw[e + 2], w3 = pw[e + 3];
        ushort2 v0 = G[(size_t)s0 * 64 + lane];
        ushort2 v1 = G[(size_t)s1 * 64 + lane];
        ushort2 v2 = G[(size_t)s2 * 64 + lane];
        ushort2 v3 = G[(size_t)s3 * 64 + lane];
        a0 += w0 * b2f(v0.x) + w1 * b2f(v1.x) + w2 * b2f(v2.x) + w3 * b2f(v3.x);
        a1 += w0 * b2f(v0.y) + w1 * b2f(v1.y) + w2 * b2f(v2.y) + w3 * b2f(v3.y);
    }
    for (; e < e1; ++e) {
        int s = psrc[e];
        float w = pw[e];
        ushort2 v = G[(size_t)s * 64 + lane];
        a0 += w * b2f(v.x); a1 += w * b2f(v.y);
    }
    float mw = mixw[0];
    float mr = 1.f / (1.f + expf(-mw));
    int c = lane * 2;
    if (c < 64) {
        float* om = out + (size_t)d * OD + c;
        om[0] = a0 * mw + om[0] * (1.f - mw);
        om[1] = a1 * mw + om[1] * (1.f - mw);
    } else {
        float* ol = out + (size_t)NN * OD + (size_t)d * OD + (c - 64);
        ol[0] = a0 * mr + ol[0] * (1.f - mr);
        ol[1] = a1 * mr + ol[1] * (1.f - mr);
    }
}

// ---------------- host ----------------

extern "C" void kernel_launch(void* const* d_in, const int* in_sizes, int n_in,
                              void* d_out, int out_size, void* d_ws, size_t ws_size,
                              hipStream_t stream) {
    const float* input = (const float*)d_in[0];
    const int*   ei    = (const int*)d_in[1];
    const float* ew    = (const float*)d_in[2];
    const float* mixw  = (const float*)d_in[3];
    const float* hw    = (const float*)d_in[4];
    const float* hb    = (const float*)d_in[5];
    const float* mw_   = (const float*)d_in[6];
    const float* mb    = (const float*)d_in[7];
    const float* lw    = (const float*)d_in[8];
    const float* lb    = (const float*)d_in[9];
    float* out = (float*)d_out;

    const int* src = ei;
    const int* dst = ei + NE;

    char* ws = (char*)d_ws;
    size_t off = 0;
    auto alloc = [&](size_t bytes) -> void* {
        void* p = ws + off;
        off += (bytes + 255) & ~(size_t)255;
        return p;
    };
    int*   deg      = (int*)alloc((size_t)NN * 4);
    int*   offsets  = (int*)alloc((size_t)(NN + 1) * 4);
    int*   cursor   = (int*)alloc((size_t)NN * 4);
    int*   chunkSum = (int*)alloc((size_t)NCH * 4);
    int*   chunkOff = (int*)alloc((size_t)NCH * 4);
    int*   psrc     = (int*)alloc((size_t)NE * 4);
    float* pw       = (float*)alloc((size_t)NE * 4);
    unsigned short* Wht  = (unsigned short*)alloc((size_t)256 * 256 * 2);
    unsigned short* Wmlt = (unsigned short*)alloc((size_t)128 * 256 * 2);
    unsigned short* support  = (unsigned short*)alloc((size_t)NN * KD * 2);
    unsigned short* hidden_g = (unsigned short*)alloc((size_t)NN * KD * 2);
    unsigned short* gcn_pre  = (unsigned short*)alloc((size_t)NN * 128 * 2);

    hipMemsetAsync(deg, 0, (size_t)NN * 4, stream);

    int eblk = (NE + 255) / 256;
    k_count<<<eblk, 256, 0, stream>>>(dst, deg);
    k_chunk_sum<<<NCH, 256, 0, stream>>>(deg, chunkSum);
    k_scan_chunks<<<1, 64, 0, stream>>>(chunkSum, chunkOff);
    k_scan_write<<<NCH, 256, 0, stream>>>(deg, chunkOff, offsets, cursor);
    k_scatter<<<eblk, 256, 0, stream>>>(src, dst, ew, cursor, psrc, pw);

    k_convW<<<256, 256, 0, stream>>>(hw, mw_, lw, Wht, Wmlt);

    int mblk = (NN + 63) / 64;
    // GEMM1: support(bf16) = bf16(input) @ hw
    k_gemm<0, 0><<<dim3(mblk, 4), 256, 0, stream>>>(input, Wht, hb, mb, lb, support, 256);
    // SpMM1 + bias + relu -> hidden_g (bf16)
    k_spmm1<<<NN, 64, 0, stream>>>(offsets, psrc, pw, support, hb, hidden_g);
    // GEMM2 (GCN): gcn_pre(bf16) = hidden_g @ [mw|lw]
    k_gemm<1, 0><<<dim3(mblk, 2), 256, 0, stream>>>(hidden_g, Wmlt, hb, mb, lb, gcn_pre, 128);
    // GEMM2 (MLP): d_out = relu(support+hb) @ [mw|lw] + [mb|lb]
    k_gemm<2, 1><<<dim3(mblk, 2), 256, 0, stream>>>(support, Wmlt, hb, mb, lb, out, 128);
    // SpMM2 + mixture combine (in place on d_out)
    k_spmm2<<<NN, 64, 0, stream>>>(offsets, psrc, pw, gcn_pre, mixw, out);
}